// Round 14
// baseline (520.671 us; speedup 1.0000x reference)
//
#include <hip/hip_runtime.h>
#include <hip/hip_bf16.h>

typedef __attribute__((ext_vector_type(8))) short short8;
typedef __attribute__((ext_vector_type(4))) short short4v;
typedef __attribute__((ext_vector_type(4))) float float4v;

#define MFMA16(a, b, c) __builtin_amdgcn_mfma_f32_16x16x32_bf16(a, b, c, 0, 0, 0)

__device__ __forceinline__ short f2bf(float f) {
    __hip_bfloat16 hb = __float2bfloat16(f);
    return *reinterpret_cast<short*>(&hb);
}
__device__ __forceinline__ float bf2f(short s) {
    __hip_bfloat16 hb = *reinterpret_cast<__hip_bfloat16*>(&s);
    return __bfloat162float(hb);
}

// ---------------------------------------------------------------------------
// Kernel 1: prep (+ fused wt).  z<8: nv/rv f32 -> Vt [b][h][64][1024] bf16 and
// Abf [b][n][512] bf16.  z==8: W[512][1024] f32 -> Wt[1024][512] bf16.
// grid: (32, 8, 9), block 256.
// ---------------------------------------------------------------------------
__global__ __launch_bounds__(256) void prep_kernel(
    const float* __restrict__ nv, const float* __restrict__ rv,
    const float* __restrict__ Wn, const float* __restrict__ Wr,
    __hip_bfloat16* __restrict__ Vtn, __hip_bfloat16* __restrict__ Vtr,
    __hip_bfloat16* __restrict__ An,  __hip_bfloat16* __restrict__ Ar,
    __hip_bfloat16* __restrict__ Wtn, __hip_bfloat16* __restrict__ Wtr)
{
    __shared__ short lds[64][72];
    const int t = threadIdx.x;

    if (blockIdx.z == 8) {
        const int id = blockIdx.x + 32 * blockIdx.y;   // 0..255
        const int c0 = (id & 15) * 64;
        const int k0 = ((id >> 4) & 7) * 64;
        const int g  = id >> 7;
        const float* W = g ? Wr : Wn;
        __hip_bfloat16* Wt = g ? Wtr : Wtn;
        {
            const int i  = t >> 2;
            const int j0 = (t & 3) * 16;
            const float* p = W + (size_t)(k0 + i) * 1024 + c0 + j0;
            #pragma unroll
            for (int jj = 0; jj < 16; ++jj)
                lds[j0 + jj][i] = f2bf(p[jj]);
        }
        __syncthreads();
        {
            const int j  = t >> 2;
            const int i0 = (t & 3) * 16;
            __hip_bfloat16* q = Wt + (size_t)(c0 + j) * 512 + k0 + i0;
            short8 v0 = *reinterpret_cast<const short8*>(&lds[j][i0]);
            short8 v1 = *reinterpret_cast<const short8*>(&lds[j][i0 + 8]);
            *reinterpret_cast<short8*>(q)     = v0;
            *reinterpret_cast<short8*>(q + 8) = v1;
        }
        return;
    }

    const int ntile = blockIdx.x & 15;
    const int src   = blockIdx.x >> 4;
    const int h     = blockIdx.y;
    const int b     = blockIdx.z;
    const float* V  = src ? rv : nv;
    __hip_bfloat16* Vt = src ? Vtr : Vtn;
    __hip_bfloat16* Ab = src ? Ar  : An;

    const int n0 = ntile * 64;
    {
        const int i  = t >> 2;
        const int j0 = (t & 3) * 16;
        const float* p = V + ((size_t)(b * 1024) + n0 + i) * 512 + h * 64 + j0;
        short8 a0, a1;
        #pragma unroll
        for (int jj = 0; jj < 8; ++jj) {
            short x = f2bf(p[jj]);
            a0[jj] = x; lds[j0 + jj][i] = x;
        }
        #pragma unroll
        for (int jj = 0; jj < 8; ++jj) {
            short x = f2bf(p[8 + jj]);
            a1[jj] = x; lds[j0 + 8 + jj][i] = x;
        }
        __hip_bfloat16* adst = Ab + ((size_t)(b * 1024) + n0 + i) * 512 + h * 64 + j0;
        *reinterpret_cast<short8*>(adst)     = a0;
        *reinterpret_cast<short8*>(adst + 8) = a1;
    }
    __syncthreads();
    {
        const int j  = t >> 2;
        const int i0 = (t & 3) * 16;
        __hip_bfloat16* q = Vt + (((size_t)(b * 8 + h) * 64) + j) * 1024 + n0 + i0;
        short8 v0 = *reinterpret_cast<const short8*>(&lds[j][i0]);
        short8 v1 = *reinterpret_cast<const short8*>(&lds[j][i0 + 8]);
        *reinterpret_cast<short8*>(q)     = v0;
        *reinterpret_cast<short8*>(q + 8) = v1;
    }
}

// ---------------------------------------------------------------------------
// Kernel 2: projection GEMM, all-bf16 inputs.  64m x 256c tile.
// grid: (128 mtiles, 4 ctiles, 2 gemms), block 256 (4 waves).
// ---------------------------------------------------------------------------
__global__ __launch_bounds__(256, 4) void proj_kernel(
    const __hip_bfloat16* __restrict__ An, const __hip_bfloat16* __restrict__ Ar,
    const __hip_bfloat16* __restrict__ Wtn, const __hip_bfloat16* __restrict__ Wtr,
    const float* __restrict__ bn, const float* __restrict__ br,
    __hip_bfloat16* __restrict__ Qn, __hip_bfloat16* __restrict__ Kn,
    __hip_bfloat16* __restrict__ Qr, __hip_bfloat16* __restrict__ Kr)
{
    const int m0 = blockIdx.x * 64;
    const int c0 = blockIdx.y * 256;
    const int g  = blockIdx.z;
    const __hip_bfloat16* A  = g ? Ar  : An;
    const __hip_bfloat16* Wt = g ? Wtr : Wtn;
    const float* bias = g ? br : bn;
    __hip_bfloat16* Qd = g ? Qr : Qn;
    __hip_bfloat16* Kd = g ? Kr : Kn;

    __shared__ short Bt[2][4][256][8];   // 32KB

    const int t    = threadIdx.x;
    const int lane = t & 63;
    const int w    = t >> 6;
    const int l15  = lane & 15;
    const int lg   = lane >> 4;

    auto stage = [&](int buf, int kk) {
        #pragma unroll
        for (int rep = 0; rep < 4; ++rep) {
            const int u = rep * 256 + t;
            const int s = u >> 8;
            const int c = u & 255;
            const __hip_bfloat16* src = Wt + (size_t)(c0 + c) * 512 + kk + s * 8;
            __builtin_amdgcn_global_load_lds(
                (const __attribute__((address_space(1))) unsigned int*)src,
                (__attribute__((address_space(3))) unsigned int*)&Bt[buf][s][c][0],
                16, 0, 0);
        }
    };

    float4v acc[16] = {};
    const int mrow = m0 + w * 16 + l15;

    stage(0, 0);
    __syncthreads();

    for (int kk = 0; kk < 512; kk += 32) {
        const int buf = (kk >> 5) & 1;
        if (kk < 480) stage(buf ^ 1, kk + 32);
        short8 afrag = *reinterpret_cast<const short8*>(
            A + (size_t)mrow * 512 + kk + lg * 8);
        #pragma unroll
        for (int cs = 0; cs < 16; ++cs) {
            short8 bfrag = *reinterpret_cast<const short8*>(
                &Bt[buf][lg][cs * 16 + l15][0]);
            acc[cs] = MFMA16(afrag, bfrag, acc[cs]);
        }
        __syncthreads();
    }

    #pragma unroll
    for (int cs = 0; cs < 16; ++cs) {
        const int c  = c0 + cs * 16 + l15;
        const bool isK = (c >= 512);
        const int hh = (c >> 6) & 7;
        const int d  = c & 63;
        __hip_bfloat16* dst = isK ? Kd : Qd;
        const float bv = bias[c];
        #pragma unroll
        for (int r = 0; r < 4; ++r) {
            const int m = m0 + w * 16 + lg * 4 + r;
            const int b = m >> 10, n = m & 1023;
            dst[(((size_t)(b * 8 + hh) * 1024 + n) * 64) + d] =
                __float2bfloat16(acc[cs][r] + bv);
        }
    }
}

// ---------------------------------------------------------------------------
// Kernel 3: attention, softmax over HEADS.  R14: 1024-thread blocks; two
// independent 8-wave groups (mh = w>>3) run the PROVEN R13 schedule on
// disjoint m-halves (softmax has no coupling across m) for the SAME 64
// output rows.  16 waves/CU = 4 waves/SIMD (2x TLP), barrier count halved.
// LDS 136KB = K_s[2] 64 + P_s[2] 40 + Xb[2] 32 -> 1 block/CU by design.
// Epilogue: mh=1's partial O added to mh=0's via K_s reused as f32 scratch.
// __launch_bounds__(1024,1): 1 block/CU => 128-VGPR cap (R13-proven fit).
// grid: (16 combos, 16 ntiles of 64 rows), XCD-local (id%8 == combo%8).
// ---------------------------------------------------------------------------
__global__ __launch_bounds__(1024, 1) void attn_kernel(
    const __hip_bfloat16* __restrict__ Qn, const __hip_bfloat16* __restrict__ Kn,
    const __hip_bfloat16* __restrict__ Qr, const __hip_bfloat16* __restrict__ Kr,
    const __hip_bfloat16* __restrict__ Vtn, const __hip_bfloat16* __restrict__ Vtr,
    float* __restrict__ out)
{
    const int combo = blockIdx.x;     // 0..15
    const int bb    = combo & 7;
    const int dir   = combo >> 3;
    const int nt    = blockIdx.y;     // 0..15
    const __hip_bfloat16* Q  = dir ? Qr  : Qn;
    const __hip_bfloat16* K  = dir ? Kn  : Kr;
    const __hip_bfloat16* Vt = dir ? Vtn : Vtr;
    float* O = out + (size_t)dir * (8u * 1024u * 512u);

    const int t    = threadIdx.x;
    const int lane = t & 63;
    const int w    = t >> 6;          // 0..15
    const int mh   = w >> 3;          // m-half group 0/1
    const int wl   = w & 7;           // wave within group
    const int iw   = wl & 1;          // n-subtile within pair
    const int hg   = wl >> 1;         // head pair 0..3
    const int h0   = hg * 2;
    const int l15  = lane & 15;
    const int lg   = lane >> 4;       // 0..3

    __shared__ short K_s[2][8 * 32 * 64];   // 64KB: [mh][h][m][d] slot-swizzled
    __shared__ short P_s[2][8][32][40];     // 40KB, wave-private regions
    __shared__ short Xb[2][2][4][2][64][8]; // 32KB bf16 [mh][ns][hg][iw][lane][p]

    const int n0 = nt * 64;
    const int mbase = mh * 512;
    const float C = 0.125f * 1.44269504f;   // SCALE * log2(e)

    const __hip_bfloat16* Vb[2] = {
        Vt + (size_t)((bb * 8 + h0)     * 64) * 1024,
        Vt + (size_t)((bb * 8 + h0 + 1) * 64) * 1024 };

    // stage 32KB K tile for group mh at m-base mt (8 waves of the group
    // cover it; 4 calls x 64 lanes x 16B per wave)
    auto stage = [&](int mt) {
        #pragma unroll
        for (int i = 0; i < 4; ++i) {
            const int u    = (wl * 4 + i) * 64 + lane;  // 16B unit, 0..2047
            const int h    = u >> 8;                    // 256 units per head
            const int mr   = (u >> 3) & 31;             // row within tile
            const int slot = (u & 7) ^ (mr & 7);        // swizzled 16B slot
            const __hip_bfloat16* g =
                K + ((size_t)((bb * 8 + h) * 1024) + mt + mr) * 64 + slot * 8;
            __builtin_amdgcn_global_load_lds(
                (const __attribute__((address_space(1))) unsigned int*)g,
                (__attribute__((address_space(3))) unsigned int*)&K_s[mh][u * 8],
                16, 0, 0);
        }
    };

    // Q fragments (B operand): qf[ns][hh][kc]  (same rows for both mh groups)
    short8 qf[2][2][2];
    #pragma unroll
    for (int ns = 0; ns < 2; ++ns)
        #pragma unroll
        for (int hh = 0; hh < 2; ++hh)
            #pragma unroll
            for (int kc = 0; kc < 2; ++kc)
                qf[ns][hh][kc] = *reinterpret_cast<const short8*>(
                    Q + ((size_t)((bb * 8 + h0 + hh) * 1024) + n0 + ns * 32 + iw * 16 + l15) * 64
                      + kc * 32 + lg * 8);

    float4v oacc[2][2][4] = {};       // [ns][hh][dd]

    stage(mbase);
    __syncthreads();                  // drain prologue staging (both groups)

    for (int it = 0; it < 16; ++it) {
        const int m0 = mbase + (it << 5);
        // ---- V frags: issue early (global, consumed at PV) ----
        short8 vf[2][4];              // [hh][dd]
        #pragma unroll
        for (int hh = 0; hh < 2; ++hh)
            #pragma unroll
            for (int dd = 0; dd < 4; ++dd)
                vf[hh][dd] = *reinterpret_cast<const short8*>(
                    Vb[hh] + (size_t)(dd * 16 + l15) * 1024 + m0 + lg * 8);
        // ---- K frags from staged LDS (swizzled slots) ----
        short8 kf[2][2][2];           // [hh][j][kc]
        const short* ks = K_s[mh];
        #pragma unroll
        for (int hh = 0; hh < 2; ++hh)
            #pragma unroll
            for (int j = 0; j < 2; ++j) {
                const int mr = j * 16 + l15;
                #pragma unroll
                for (int kc = 0; kc < 2; ++kc)
                    kf[hh][j][kc] = *reinterpret_cast<const short8*>(
                        ks + (h0 + hh) * 2048 + mr * 64
                           + (((kc * 4 + lg) ^ (mr & 7)) * 8));
            }

        #pragma unroll
        for (int ns = 0; ns < 2; ++ns) {
            // ---- S^T = K Q^T, exp in-register ----
            float4v sacc[2][2] = {};  // [hh][j]
            #pragma unroll
            for (int hh = 0; hh < 2; ++hh)
                #pragma unroll
                for (int j = 0; j < 2; ++j)
                    #pragma unroll
                    for (int kc = 0; kc < 2; ++kc)
                        sacc[hh][j] = MFMA16(kf[hh][j][kc], qf[ns][hh][kc], sacc[hh][j]);
            float e[2][8];
            float ps[8] = {0.f, 0.f, 0.f, 0.f, 0.f, 0.f, 0.f, 0.f};
            #pragma unroll
            for (int hh = 0; hh < 2; ++hh)
                #pragma unroll
                for (int j = 0; j < 2; ++j)
                    #pragma unroll
                    for (int r = 0; r < 4; ++r) {
                        float ev = exp2f(sacc[hh][j][r] * C);
                        e[hh][j * 4 + r] = ev;
                        ps[j * 4 + r] += ev;
                    }
            // ---- exchange head-partial sums (bf16-packed, b128 ops) ----
            {
                short8 pk;
                #pragma unroll
                for (int p = 0; p < 8; ++p) pk[p] = f2bf(ps[p]);
                *reinterpret_cast<short8*>(&Xb[mh][ns][hg][iw][lane][0]) = pk;
            }
            __syncthreads();
            if (ns == 0)   // stage group's next K tile into its buffer
                stage((it < 15) ? m0 + 32 : mbase);
            float inv[8];
            {
                float tot[8];
                #pragma unroll
                for (int p = 0; p < 8; ++p) tot[p] = ps[p];
                #pragma unroll
                for (int g = 1; g < 4; ++g) {
                    short8 x = *reinterpret_cast<const short8*>(
                        &Xb[mh][ns][(hg + g) & 3][iw][lane][0]);
                    #pragma unroll
                    for (int p = 0; p < 8; ++p) tot[p] += bf2f(x[p]);
                }
                #pragma unroll
                for (int p = 0; p < 8; ++p)
                    inv[p] = __builtin_amdgcn_rcpf(tot[p]);
            }
            // ---- P = e * inv -> wave-private P_s (b64 packed) ----
            #pragma unroll
            for (int hh = 0; hh < 2; ++hh)
                #pragma unroll
                for (int j = 0; j < 2; ++j) {
                    short4v pk;
                    #pragma unroll
                    for (int r = 0; r < 4; ++r)
                        pk[r] = f2bf(e[hh][j * 4 + r] * inv[j * 4 + r]);
                    *reinterpret_cast<short4v*>(
                        &P_s[mh][h0 + hh][iw * 16 + l15][j * 16 + lg * 4]) = pk;
                }
            // ---- O += P V ----
            #pragma unroll
            for (int hh = 0; hh < 2; ++hh) {
                short8 pf = *reinterpret_cast<const short8*>(
                    &P_s[mh][h0 + hh][iw * 16 + l15][lg * 8]);
                #pragma unroll
                for (int dd = 0; dd < 4; ++dd)
                    oacc[ns][hh][dd] = MFMA16(pf, vf[hh][dd], oacc[ns][hh][dd]);
            }
        }
        __syncthreads();              // fences X slots + drains staging DMA
    }

    // ---- combine mh=1 partials into mh=0 via K_s reused as f32 scratch ----
    // scratch layout: sc[(wl*32 + v)*64 + lane], v = hh*16 + dd*4 + r  (64KB)
    float* sc = reinterpret_cast<float*>(&K_s[0][0]);
    __syncthreads();
    #pragma unroll
    for (int ns = 0; ns < 2; ++ns) {
        if (mh == 1) {
            #pragma unroll
            for (int hh = 0; hh < 2; ++hh)
                #pragma unroll
                for (int dd = 0; dd < 4; ++dd)
                    #pragma unroll
                    for (int r = 0; r < 4; ++r)
                        sc[(wl * 32 + hh * 16 + dd * 4 + r) * 64 + lane] =
                            oacc[ns][hh][dd][r];
        }
        __syncthreads();
        if (mh == 0) {
            #pragma unroll
            for (int hh = 0; hh < 2; ++hh)
                #pragma unroll
                for (int dd = 0; dd < 4; ++dd)
                    #pragma unroll
                    for (int r = 0; r < 4; ++r)
                        oacc[ns][hh][dd][r] +=
                            sc[(wl * 32 + hh * 16 + dd * 4 + r) * 64 + lane];
        }
        __syncthreads();
    }

    // ---- epilogue (mh=0 waves): O[b][n][h*64+d] f32 ----
    if (mh == 0) {
        #pragma unroll
        for (int ns = 0; ns < 2; ++ns)
            #pragma unroll
            for (int hh = 0; hh < 2; ++hh)
                #pragma unroll
                for (int dd = 0; dd < 4; ++dd)
                    #pragma unroll
                    for (int r = 0; r < 4; ++r) {
                        const int n = n0 + ns * 32 + iw * 16 + lg * 4 + r;
                        const int d = dd * 16 + l15;
                        O[((size_t)(bb * 1024) + n) * 512 + (h0 + hh) * 64 + d] =
                            oacc[ns][hh][dd][r];
                    }
    }
}

extern "C" void kernel_launch(void* const* d_in, const int* in_sizes, int n_in,
                              void* d_out, int out_size, void* d_ws, size_t ws_size,
                              hipStream_t stream) {
    const float* nv = (const float*)d_in[0];
    const float* rv = (const float*)d_in[1];
    const float* Wn = (const float*)d_in[2];
    const float* bn = (const float*)d_in[3];
    const float* Wr = (const float*)d_in[4];
    const float* br = (const float*)d_in[5];
    float* out = (float*)d_out;

    __hip_bfloat16* w = (__hip_bfloat16*)d_ws;
    const size_t E = 8ull * 8 * 1024 * 64;    // 4M elems
    __hip_bfloat16* Qn  = w;
    __hip_bfloat16* Kn  = w + E;
    __hip_bfloat16* Qr  = w + 2 * E;
    __hip_bfloat16* Kr  = w + 3 * E;
    __hip_bfloat16* Vtn = w + 4 * E;
    __hip_bfloat16* Vtr = w + 5 * E;
    __hip_bfloat16* An  = w + 6 * E;
    __hip_bfloat16* Ar  = w + 7 * E;
    __hip_bfloat16* Wtn = w + 8 * E;
    __hip_bfloat16* Wtr = w + 8 * E + 512 * 1024;

    prep_kernel<<<dim3(32, 8, 9), 256, 0, stream>>>(nv, rv, Wn, Wr,
                                                    Vtn, Vtr, An, Ar, Wtn, Wtr);
    proj_kernel<<<dim3(128, 4, 2), 256, 0, stream>>>(An, Ar, Wtn, Wtr, bn, br,
                                                     Qn, Kn, Qr, Kr);
    attn_kernel<<<dim3(16, 16), 1024, 0, stream>>>(Qn, Kn, Qr, Kr, Vtn, Vtr, out);
}

// Round 15
// 169.730 us; speedup vs baseline: 3.0676x; 3.0676x over previous
//
#include <hip/hip_runtime.h>
#include <hip/hip_bf16.h>

typedef __attribute__((ext_vector_type(8))) short short8;
typedef __attribute__((ext_vector_type(4))) short short4v;
typedef __attribute__((ext_vector_type(4))) float float4v;

#define MFMA16(a, b, c) __builtin_amdgcn_mfma_f32_16x16x32_bf16(a, b, c, 0, 0, 0)

__device__ __forceinline__ short f2bf(float f) {
    __hip_bfloat16 hb = __float2bfloat16(f);
    return *reinterpret_cast<short*>(&hb);
}

// ---------------------------------------------------------------------------
// Kernel 1: prep (+ fused wt).  z<8: nv/rv f32 -> Vt [b][h][64][1024] bf16.
// z==8: W[512][1024] f32 -> Wt[1024][512] bf16.  grid: (32, 8, 9), block 256.
// (A-bf16 output dropped in R15: proj reads f32 A directly.)
// ---------------------------------------------------------------------------
__global__ __launch_bounds__(256) void prep_kernel(
    const float* __restrict__ nv, const float* __restrict__ rv,
    const float* __restrict__ Wn, const float* __restrict__ Wr,
    __hip_bfloat16* __restrict__ Vtn, __hip_bfloat16* __restrict__ Vtr,
    __hip_bfloat16* __restrict__ Wtn, __hip_bfloat16* __restrict__ Wtr)
{
    __shared__ short lds[64][72];
    const int t = threadIdx.x;

    if (blockIdx.z == 8) {
        // ---- wt part: 256 blocks = 16 ctiles x 8 ktiles x 2 gemms ----
        const int id = blockIdx.x + 32 * blockIdx.y;   // 0..255
        const int c0 = (id & 15) * 64;
        const int k0 = ((id >> 4) & 7) * 64;
        const int g  = id >> 7;
        const float* W = g ? Wr : Wn;
        __hip_bfloat16* Wt = g ? Wtr : Wtn;
        {
            const int i  = t >> 2;            // k row
            const int j0 = (t & 3) * 16;      // c chunk
            const float* p = W + (size_t)(k0 + i) * 1024 + c0 + j0;
            #pragma unroll
            for (int jj = 0; jj < 16; ++jj)
                lds[j0 + jj][i] = f2bf(p[jj]);  // lds[c][k]
        }
        __syncthreads();
        {
            const int j  = t >> 2;            // c row
            const int i0 = (t & 3) * 16;      // k chunk
            __hip_bfloat16* q = Wt + (size_t)(c0 + j) * 512 + k0 + i0;
            short8 v0 = *reinterpret_cast<const short8*>(&lds[j][i0]);
            short8 v1 = *reinterpret_cast<const short8*>(&lds[j][i0 + 8]);
            *reinterpret_cast<short8*>(q)     = v0;
            *reinterpret_cast<short8*>(q + 8) = v1;
        }
        return;
    }

    // ---- V-transpose part ----
    const int ntile = blockIdx.x & 15;
    const int src   = blockIdx.x >> 4;
    const int h     = blockIdx.y;
    const int b     = blockIdx.z;
    const float* V  = src ? rv : nv;
    __hip_bfloat16* Vt = src ? Vtr : Vtn;

    const int n0 = ntile * 64;
    {
        const int i  = t >> 2;            // n within tile
        const int j0 = (t & 3) * 16;      // d chunk
        const float* p = V + ((size_t)(b * 1024) + n0 + i) * 512 + h * 64 + j0;
        #pragma unroll
        for (int jj = 0; jj < 16; ++jj)
            lds[j0 + jj][i] = f2bf(p[jj]);
    }
    __syncthreads();
    {
        const int j  = t >> 2;            // d row
        const int i0 = (t & 3) * 16;      // n chunk
        __hip_bfloat16* q = Vt + (((size_t)(b * 8 + h) * 64) + j) * 1024 + n0 + i0;
        short8 v0 = *reinterpret_cast<const short8*>(&lds[j][i0]);
        short8 v1 = *reinterpret_cast<const short8*>(&lds[j][i0 + 8]);
        *reinterpret_cast<short8*>(q)     = v0;
        *reinterpret_cast<short8*>(q + 8) = v1;
    }
}

// ---------------------------------------------------------------------------
// Kernel 2: projection GEMM.  A read as f32 DIRECTLY from nv/rv (convert
// in-register; L3 serves the 4x c-tile re-reads).  64m x 256c tile.
// Wt bf16 panel staged via global_load_lds (slot-major, linear dest), dbuf.
// grid: (128 mtiles, 4 ctiles, 2 gemms), block 256 (4 waves).
// ---------------------------------------------------------------------------
__global__ __launch_bounds__(256, 4) void proj_kernel(
    const float* __restrict__ nv, const float* __restrict__ rv,
    const __hip_bfloat16* __restrict__ Wtn, const __hip_bfloat16* __restrict__ Wtr,
    const float* __restrict__ bn, const float* __restrict__ br,
    __hip_bfloat16* __restrict__ Qn, __hip_bfloat16* __restrict__ Kn,
    __hip_bfloat16* __restrict__ Qr, __hip_bfloat16* __restrict__ Kr)
{
    const int m0 = blockIdx.x * 64;
    const int c0 = blockIdx.y * 256;
    const int g  = blockIdx.z;
    const float* A = g ? rv : nv;            // [8192][512] f32 row-major
    const __hip_bfloat16* Wt = g ? Wtr : Wtn;
    const float* bias = g ? br : bn;
    __hip_bfloat16* Qd = g ? Qr : Qn;
    __hip_bfloat16* Kd = g ? Kr : Kn;

    __shared__ short Bt[2][4][256][8];   // [buf][k-slot][c][8 bf16] = 32KB

    const int t    = threadIdx.x;
    const int lane = t & 63;
    const int w    = t >> 6;
    const int l15  = lane & 15;
    const int lg   = lane >> 4;

    auto stage = [&](int buf, int kk) {
        #pragma unroll
        for (int rep = 0; rep < 4; ++rep) {
            const int u = rep * 256 + t;        // 16B unit 0..1023
            const int s = u >> 8;               // k-slot 0..3
            const int c = u & 255;
            const __hip_bfloat16* src = Wt + (size_t)(c0 + c) * 512 + kk + s * 8;
            __builtin_amdgcn_global_load_lds(
                (const __attribute__((address_space(1))) unsigned int*)src,
                (__attribute__((address_space(3))) unsigned int*)&Bt[buf][s][c][0],
                16, 0, 0);
        }
    };

    float4v acc[16] = {};
    const int mrow = m0 + w * 16 + l15;

    stage(0, 0);
    __syncthreads();

    for (int kk = 0; kk < 512; kk += 32) {
        const int buf = (kk >> 5) & 1;
        if (kk < 480) stage(buf ^ 1, kk + 32);
        // A fragment: 8 consecutive k at fixed row, f32 -> bf16 in-register
        short8 afrag;
        {
            const float* ap = A + (size_t)mrow * 512 + kk + lg * 8;
            float4 a0 = *reinterpret_cast<const float4*>(ap);
            float4 a1 = *reinterpret_cast<const float4*>(ap + 4);
            short* af = (short*)&afrag;
            af[0] = f2bf(a0.x); af[1] = f2bf(a0.y); af[2] = f2bf(a0.z); af[3] = f2bf(a0.w);
            af[4] = f2bf(a1.x); af[5] = f2bf(a1.y); af[6] = f2bf(a1.z); af[7] = f2bf(a1.w);
        }
        #pragma unroll
        for (int cs = 0; cs < 16; ++cs) {
            short8 bfrag = *reinterpret_cast<const short8*>(
                &Bt[buf][lg][cs * 16 + l15][0]);
            acc[cs] = MFMA16(afrag, bfrag, acc[cs]);
        }
        __syncthreads();
    }

    #pragma unroll
    for (int cs = 0; cs < 16; ++cs) {
        const int c  = c0 + cs * 16 + l15;
        const bool isK = (c >= 512);
        const int hh = (c >> 6) & 7;
        const int d  = c & 63;
        __hip_bfloat16* dst = isK ? Kd : Qd;
        const float bv = bias[c];
        #pragma unroll
        for (int r = 0; r < 4; ++r) {
            const int m = m0 + w * 16 + lg * 4 + r;
            const int b = m >> 10, n = m & 1023;
            dst[(((size_t)(b * 8 + hh) * 1024 + n) * 64) + d] =
                __float2bfloat16(acc[cs][r] + bv);
        }
    }
}

// ---------------------------------------------------------------------------
// Kernel 3: attention, softmax over HEADS.  R10's kernel VERBATIM (fastest
// measured: 117-118us; VGPR 128, LDS 118784, FETCH ~24.7MB).
// grid: (16 combos = b + 8*dir, 16 ntiles of 64 rows) -> 256 blocks, 1/CU,
// XCD-local (id%8 == combo%8). block 512 (8 waves: hg head-pair x iw).
// K tile (8 heads x 32m x 64d = 32KB) DMA-staged, double-buffered, slot-XOR
// swizzled. V frags register loads at iter top. Scalar f32 X exchange.
// Stage issued after ns0's barrier; drains at end-of-iter barrier.
// ---------------------------------------------------------------------------
__global__ __launch_bounds__(512, 2) void attn_kernel(
    const __hip_bfloat16* __restrict__ Qn, const __hip_bfloat16* __restrict__ Kn,
    const __hip_bfloat16* __restrict__ Qr, const __hip_bfloat16* __restrict__ Kr,
    const __hip_bfloat16* __restrict__ Vtn, const __hip_bfloat16* __restrict__ Vtr,
    float* __restrict__ out)
{
    const int combo = blockIdx.x;     // 0..15
    const int bb    = combo & 7;
    const int dir   = combo >> 3;
    const int nt    = blockIdx.y;     // 0..15
    const __hip_bfloat16* Q  = dir ? Qr  : Qn;
    const __hip_bfloat16* K  = dir ? Kn  : Kr;
    const __hip_bfloat16* Vt = dir ? Vtn : Vtr;
    float* O = out + (size_t)dir * (8u * 1024u * 512u);

    const int t    = threadIdx.x;
    const int lane = t & 63;
    const int w    = t >> 6;          // 0..7
    const int iw   = w & 1;           // n-subtile within pair
    const int hg   = w >> 1;          // head pair 0..3
    const int h0   = hg * 2;
    const int l15  = lane & 15;
    const int lg   = lane >> 4;       // 0..3

    __shared__ short K_s[2][8 * 32 * 64];   // 64KB: [buf][h][m][d] (slot-swizzled)
    __shared__ short P_s[8][32][40];        // 20KB, wave-private regions
    __shared__ float X_s[2][4][2][512];     // 32KB [ns][hg][iw][p*64+lane]

    const int n0 = nt * 64;
    const float C = 0.125f * 1.44269504f;   // SCALE * log2(e)

    const __hip_bfloat16* Vb[2] = {
        Vt + (size_t)((bb * 8 + h0)     * 64) * 1024,
        Vt + (size_t)((bb * 8 + h0 + 1) * 64) * 1024 };

    auto stage = [&](int bufn, int mt) {
        #pragma unroll
        for (int i = 0; i < 4; ++i) {
            const int u    = (w * 4 + i) * 64 + lane;   // 16B unit, 0..2047
            const int h    = u >> 8;                    // 256 units per head
            const int mr   = (u >> 3) & 31;             // row within tile
            const int slot = (u & 7) ^ (mr & 7);        // swizzled 16B slot
            const __hip_bfloat16* g =
                K + ((size_t)((bb * 8 + h) * 1024) + mt + mr) * 64 + slot * 8;
            __builtin_amdgcn_global_load_lds(
                (const __attribute__((address_space(1))) unsigned int*)g,
                (__attribute__((address_space(3))) unsigned int*)&K_s[bufn][u * 8],
                16, 0, 0);
        }
    };

    // Q fragments (B operand): qf[ns][hh][kc]
    short8 qf[2][2][2];
    #pragma unroll
    for (int ns = 0; ns < 2; ++ns)
        #pragma unroll
        for (int hh = 0; hh < 2; ++hh)
            #pragma unroll
            for (int kc = 0; kc < 2; ++kc)
                qf[ns][hh][kc] = *reinterpret_cast<const short8*>(
                    Q + ((size_t)((bb * 8 + h0 + hh) * 1024) + n0 + ns * 32 + iw * 16 + l15) * 64
                      + kc * 32 + lg * 8);

    float4v oacc[2][2][4] = {};       // [ns][hh][dd]

    stage(0, 0);
    __syncthreads();                  // drain prologue staging

    for (int it = 0; it < 32; ++it) {
        const int m0  = it << 5;
        const int buf = it & 1;
        // ---- V frags: issue early (global, consumed at PV) ----
        short8 vf[2][4];              // [hh][dd]
        #pragma unroll
        for (int hh = 0; hh < 2; ++hh)
            #pragma unroll
            for (int dd = 0; dd < 4; ++dd)
                vf[hh][dd] = *reinterpret_cast<const short8*>(
                    Vb[hh] + (size_t)(dd * 16 + l15) * 1024 + m0 + lg * 8);
        // ---- K frags from staged LDS (swizzled slots) ----
        short8 kf[2][2][2];           // [hh][j][kc]
        const short* ks = K_s[buf];
        #pragma unroll
        for (int hh = 0; hh < 2; ++hh)
            #pragma unroll
            for (int j = 0; j < 2; ++j) {
                const int mr = j * 16 + l15;
                #pragma unroll
                for (int kc = 0; kc < 2; ++kc)
                    kf[hh][j][kc] = *reinterpret_cast<const short8*>(
                        ks + (h0 + hh) * 2048 + mr * 64
                           + (((kc * 4 + lg) ^ (mr & 7)) * 8));
            }

        #pragma unroll
        for (int ns = 0; ns < 2; ++ns) {
            // ---- S^T = K Q^T, exp in-register ----
            float4v sacc[2][2] = {};  // [hh][j]
            #pragma unroll
            for (int hh = 0; hh < 2; ++hh)
                #pragma unroll
                for (int j = 0; j < 2; ++j)
                    #pragma unroll
                    for (int kc = 0; kc < 2; ++kc)
                        sacc[hh][j] = MFMA16(kf[hh][j][kc], qf[ns][hh][kc], sacc[hh][j]);
            float e[2][8];
            float ps[8] = {0.f, 0.f, 0.f, 0.f, 0.f, 0.f, 0.f, 0.f};
            #pragma unroll
            for (int hh = 0; hh < 2; ++hh)
                #pragma unroll
                for (int j = 0; j < 2; ++j)
                    #pragma unroll
                    for (int r = 0; r < 4; ++r) {
                        float ev = exp2f(sacc[hh][j][r] * C);
                        e[hh][j * 4 + r] = ev;
                        ps[j * 4 + r] += ev;
                    }
            // ---- exchange head-partial sums (scalar, conflict-free) ----
            #pragma unroll
            for (int p = 0; p < 8; ++p)
                X_s[ns][hg][iw][p * 64 + lane] = ps[p];
            __syncthreads();
            if (ns == 0)   // stage next iter's K; drains at end-of-iter barrier
                stage(buf ^ 1, (it < 31) ? m0 + 32 : 0);
            float inv[8];
            #pragma unroll
            for (int p = 0; p < 8; ++p) {
                float tot = ps[p];
                #pragma unroll
                for (int g = 1; g < 4; ++g)
                    tot += X_s[ns][(hg + g) & 3][iw][p * 64 + lane];
                inv[p] = __builtin_amdgcn_rcpf(tot);
            }
            // ---- P = e * inv -> wave-private P_s (b64 packed) ----
            #pragma unroll
            for (int hh = 0; hh < 2; ++hh)
                #pragma unroll
                for (int j = 0; j < 2; ++j) {
                    short4v pk;
                    #pragma unroll
                    for (int r = 0; r < 4; ++r)
                        pk[r] = f2bf(e[hh][j * 4 + r] * inv[j * 4 + r]);
                    *reinterpret_cast<short4v*>(
                        &P_s[h0 + hh][iw * 16 + l15][j * 16 + lg * 4]) = pk;
                }
            // ---- O += P V (P_s wave-private: in-wave LDS ordering suffices) ----
            #pragma unroll
            for (int hh = 0; hh < 2; ++hh) {
                short8 pf = *reinterpret_cast<const short8*>(
                    &P_s[h0 + hh][iw * 16 + l15][lg * 8]);
                #pragma unroll
                for (int dd = 0; dd < 4; ++dd)
                    oacc[ns][hh][dd] = MFMA16(pf, vf[hh][dd], oacc[ns][hh][dd]);
            }
        }
        __syncthreads();              // fences X slots + drains staging DMA
    }

    // ---- epilogue: O[b][n][h*64+d] f32 ----
    #pragma unroll
    for (int ns = 0; ns < 2; ++ns)
        #pragma unroll
        for (int hh = 0; hh < 2; ++hh)
            #pragma unroll
            for (int dd = 0; dd < 4; ++dd)
                #pragma unroll
                for (int r = 0; r < 4; ++r) {
                    const int n = n0 + ns * 32 + iw * 16 + lg * 4 + r;
                    const int d = dd * 16 + l15;
                    O[((size_t)(bb * 1024) + n) * 512 + (h0 + hh) * 64 + d] =
                        oacc[ns][hh][dd][r];
                }
}

extern "C" void kernel_launch(void* const* d_in, const int* in_sizes, int n_in,
                              void* d_out, int out_size, void* d_ws, size_t ws_size,
                              hipStream_t stream) {
    const float* nv = (const float*)d_in[0];
    const float* rv = (const float*)d_in[1];
    const float* Wn = (const float*)d_in[2];
    const float* bn = (const float*)d_in[3];
    const float* Wr = (const float*)d_in[4];
    const float* br = (const float*)d_in[5];
    float* out = (float*)d_out;

    __hip_bfloat16* w = (__hip_bfloat16*)d_ws;
    const size_t E = 8ull * 8 * 1024 * 64;    // 4M elems
    __hip_bfloat16* Qn  = w;
    __hip_bfloat16* Kn  = w + E;
    __hip_bfloat16* Qr  = w + 2 * E;
    __hip_bfloat16* Kr  = w + 3 * E;
    __hip_bfloat16* Vtn = w + 4 * E;
    __hip_bfloat16* Vtr = w + 5 * E;
    __hip_bfloat16* Wtn = w + 6 * E;
    __hip_bfloat16* Wtr = w + 6 * E + 512 * 1024;

    prep_kernel<<<dim3(32, 8, 9), 256, 0, stream>>>(nv, rv, Wn, Wr,
                                                    Vtn, Vtr, Wtn, Wtr);
    proj_kernel<<<dim3(128, 4, 2), 256, 0, stream>>>(nv, rv, Wtn, Wtr, bn, br,
                                                     Qn, Kn, Qr, Kr);
    attn_kernel<<<dim3(16, 16), 512, 0, stream>>>(Qn, Kn, Qr, Kr, Vtn, Vtr, out);
}

// Round 16
// 165.136 us; speedup vs baseline: 3.1530x; 1.0278x over previous
//
#include <hip/hip_runtime.h>
#include <hip/hip_bf16.h>

typedef __attribute__((ext_vector_type(8))) short short8;
typedef __attribute__((ext_vector_type(4))) short short4v;
typedef __attribute__((ext_vector_type(4))) float float4v;

#define MFMA16(a, b, c) __builtin_amdgcn_mfma_f32_16x16x32_bf16(a, b, c, 0, 0, 0)

__device__ __forceinline__ short f2bf(float f) {
    __hip_bfloat16 hb = __float2bfloat16(f);
    return *reinterpret_cast<short*>(&hb);
}

// ---------------------------------------------------------------------------
// Kernel 1: prep (+ fused wt).  z<8: nv/rv f32 -> Vt [b][h][64][1024] bf16.
// z==8: W[512][1024] f32 -> Wt[1024][512] bf16.  grid: (32, 8, 9), block 256.
// (verbatim from R15)
// ---------------------------------------------------------------------------
__global__ __launch_bounds__(256) void prep_kernel(
    const float* __restrict__ nv, const float* __restrict__ rv,
    const float* __restrict__ Wn, const float* __restrict__ Wr,
    __hip_bfloat16* __restrict__ Vtn, __hip_bfloat16* __restrict__ Vtr,
    __hip_bfloat16* __restrict__ Wtn, __hip_bfloat16* __restrict__ Wtr)
{
    __shared__ short lds[64][72];
    const int t = threadIdx.x;

    if (blockIdx.z == 8) {
        // ---- wt part: 256 blocks = 16 ctiles x 8 ktiles x 2 gemms ----
        const int id = blockIdx.x + 32 * blockIdx.y;   // 0..255
        const int c0 = (id & 15) * 64;
        const int k0 = ((id >> 4) & 7) * 64;
        const int g  = id >> 7;
        const float* W = g ? Wr : Wn;
        __hip_bfloat16* Wt = g ? Wtr : Wtn;
        {
            const int i  = t >> 2;            // k row
            const int j0 = (t & 3) * 16;      // c chunk
            const float* p = W + (size_t)(k0 + i) * 1024 + c0 + j0;
            #pragma unroll
            for (int jj = 0; jj < 16; ++jj)
                lds[j0 + jj][i] = f2bf(p[jj]);  // lds[c][k]
        }
        __syncthreads();
        {
            const int j  = t >> 2;            // c row
            const int i0 = (t & 3) * 16;      // k chunk
            __hip_bfloat16* q = Wt + (size_t)(c0 + j) * 512 + k0 + i0;
            short8 v0 = *reinterpret_cast<const short8*>(&lds[j][i0]);
            short8 v1 = *reinterpret_cast<const short8*>(&lds[j][i0 + 8]);
            *reinterpret_cast<short8*>(q)     = v0;
            *reinterpret_cast<short8*>(q + 8) = v1;
        }
        return;
    }

    // ---- V-transpose part ----
    const int ntile = blockIdx.x & 15;
    const int src   = blockIdx.x >> 4;
    const int h     = blockIdx.y;
    const int b     = blockIdx.z;
    const float* V  = src ? rv : nv;
    __hip_bfloat16* Vt = src ? Vtr : Vtn;

    const int n0 = ntile * 64;
    {
        const int i  = t >> 2;            // n within tile
        const int j0 = (t & 3) * 16;      // d chunk
        const float* p = V + ((size_t)(b * 1024) + n0 + i) * 512 + h * 64 + j0;
        #pragma unroll
        for (int jj = 0; jj < 16; ++jj)
            lds[j0 + jj][i] = f2bf(p[jj]);
    }
    __syncthreads();
    {
        const int j  = t >> 2;            // d row
        const int i0 = (t & 3) * 16;      // n chunk
        __hip_bfloat16* q = Vt + (((size_t)(b * 8 + h) * 64) + j) * 1024 + n0 + i0;
        short8 v0 = *reinterpret_cast<const short8*>(&lds[j][i0]);
        short8 v1 = *reinterpret_cast<const short8*>(&lds[j][i0 + 8]);
        *reinterpret_cast<short8*>(q)     = v0;
        *reinterpret_cast<short8*>(q + 8) = v1;
    }
}

// ---------------------------------------------------------------------------
// Kernel 2: projection GEMM.  R16: 128m x 256c tile — each wave owns TWO
// 16-row m-fragments, so each B ds_read_b128 feeds 2 MFMAs (total ds_reads
// halved; proj was LDS-read-issue-bound: 16 reads ~192cyc vs 16 MFMA ~80cyc).
// A read f32 directly from nv/rv (cvt in-register; L3 serves re-reads).
// acc[2][16] = 128 VGPR -> __launch_bounds__(256,2) (256-reg budget, the
// only bound that never spilled this session).  LDS 32KB, dbuf, 1 barrier/it.
// grid: (64 mtiles, 4 ctiles, 2 gemms) = 512 blocks, block 256 (4 waves).
// ---------------------------------------------------------------------------
__global__ __launch_bounds__(256, 2) void proj_kernel(
    const float* __restrict__ nv, const float* __restrict__ rv,
    const __hip_bfloat16* __restrict__ Wtn, const __hip_bfloat16* __restrict__ Wtr,
    const float* __restrict__ bn, const float* __restrict__ br,
    __hip_bfloat16* __restrict__ Qn, __hip_bfloat16* __restrict__ Kn,
    __hip_bfloat16* __restrict__ Qr, __hip_bfloat16* __restrict__ Kr)
{
    const int m0 = blockIdx.x * 128;
    const int c0 = blockIdx.y * 256;
    const int g  = blockIdx.z;
    const float* A = g ? rv : nv;            // [8192][512] f32 row-major
    const __hip_bfloat16* Wt = g ? Wtr : Wtn;
    const float* bias = g ? br : bn;
    __hip_bfloat16* Qd = g ? Qr : Qn;
    __hip_bfloat16* Kd = g ? Kr : Kn;

    __shared__ short Bt[2][4][256][8];   // [buf][k-slot][c][8 bf16] = 32KB

    const int t    = threadIdx.x;
    const int lane = t & 63;
    const int w    = t >> 6;
    const int l15  = lane & 15;
    const int lg   = lane >> 4;

    auto stage = [&](int buf, int kk) {
        #pragma unroll
        for (int rep = 0; rep < 4; ++rep) {
            const int u = rep * 256 + t;        // 16B unit 0..1023
            const int s = u >> 8;               // k-slot 0..3
            const int c = u & 255;
            const __hip_bfloat16* src = Wt + (size_t)(c0 + c) * 512 + kk + s * 8;
            __builtin_amdgcn_global_load_lds(
                (const __attribute__((address_space(1))) unsigned int*)src,
                (__attribute__((address_space(3))) unsigned int*)&Bt[buf][s][c][0],
                16, 0, 0);
        }
    };

    float4v acc[2][16] = {};                 // [mi][cs] = 128 VGPR
    const int mrow0 = m0 + w * 32 + l15;     // wave owns rows [w*32, w*32+32)

    stage(0, 0);
    __syncthreads();

    for (int kk = 0; kk < 512; kk += 32) {
        const int buf = (kk >> 5) & 1;
        if (kk < 480) stage(buf ^ 1, kk + 32);
        // Two A fragments (rows mrow0, mrow0+16), f32 -> bf16 in-register
        short8 afrag[2];
        #pragma unroll
        for (int mi = 0; mi < 2; ++mi) {
            const float* ap = A + (size_t)(mrow0 + mi * 16) * 512 + kk + lg * 8;
            float4 a0 = *reinterpret_cast<const float4*>(ap);
            float4 a1 = *reinterpret_cast<const float4*>(ap + 4);
            short* af = (short*)&afrag[mi];
            af[0] = f2bf(a0.x); af[1] = f2bf(a0.y); af[2] = f2bf(a0.z); af[3] = f2bf(a0.w);
            af[4] = f2bf(a1.x); af[5] = f2bf(a1.y); af[6] = f2bf(a1.z); af[7] = f2bf(a1.w);
        }
        #pragma unroll
        for (int cs = 0; cs < 16; ++cs) {
            short8 bfrag = *reinterpret_cast<const short8*>(
                &Bt[buf][lg][cs * 16 + l15][0]);
            acc[0][cs] = MFMA16(afrag[0], bfrag, acc[0][cs]);
            acc[1][cs] = MFMA16(afrag[1], bfrag, acc[1][cs]);
        }
        __syncthreads();
    }

    #pragma unroll
    for (int cs = 0; cs < 16; ++cs) {
        const int c  = c0 + cs * 16 + l15;
        const bool isK = (c >= 512);
        const int hh = (c >> 6) & 7;
        const int d  = c & 63;
        __hip_bfloat16* dst = isK ? Kd : Qd;
        const float bv = bias[c];
        #pragma unroll
        for (int mi = 0; mi < 2; ++mi)
            #pragma unroll
            for (int r = 0; r < 4; ++r) {
                const int m = m0 + w * 32 + mi * 16 + lg * 4 + r;
                const int b = m >> 10, n = m & 1023;
                dst[(((size_t)(b * 8 + hh) * 1024 + n) * 64) + d] =
                    __float2bfloat16(acc[mi][cs][r] + bv);
            }
    }
}

// ---------------------------------------------------------------------------
// Kernel 3: attention, softmax over HEADS.  R10's kernel VERBATIM (fastest
// measured: 117-118us; VGPR 128, LDS 118784, FETCH ~24.7MB).
// grid: (16 combos = b + 8*dir, 16 ntiles of 64 rows) -> 256 blocks, 1/CU,
// XCD-local (id%8 == combo%8). block 512 (8 waves: hg head-pair x iw).
// K tile (8 heads x 32m x 64d = 32KB) DMA-staged, double-buffered, slot-XOR
// swizzled. V frags register loads at iter top. Scalar f32 X exchange.
// Stage issued after ns0's barrier; drains at end-of-iter barrier.
// ---------------------------------------------------------------------------
__global__ __launch_bounds__(512, 2) void attn_kernel(
    const __hip_bfloat16* __restrict__ Qn, const __hip_bfloat16* __restrict__ Kn,
    const __hip_bfloat16* __restrict__ Qr, const __hip_bfloat16* __restrict__ Kr,
    const __hip_bfloat16* __restrict__ Vtn, const __hip_bfloat16* __restrict__ Vtr,
    float* __restrict__ out)
{
    const int combo = blockIdx.x;     // 0..15
    const int bb    = combo & 7;
    const int dir   = combo >> 3;
    const int nt    = blockIdx.y;     // 0..15
    const __hip_bfloat16* Q  = dir ? Qr  : Qn;
    const __hip_bfloat16* K  = dir ? Kn  : Kr;
    const __hip_bfloat16* Vt = dir ? Vtn : Vtr;
    float* O = out + (size_t)dir * (8u * 1024u * 512u);

    const int t    = threadIdx.x;
    const int lane = t & 63;
    const int w    = t >> 6;          // 0..7
    const int iw   = w & 1;           // n-subtile within pair
    const int hg   = w >> 1;          // head pair 0..3
    const int h0   = hg * 2;
    const int l15  = lane & 15;
    const int lg   = lane >> 4;       // 0..3

    __shared__ short K_s[2][8 * 32 * 64];   // 64KB: [buf][h][m][d] (slot-swizzled)
    __shared__ short P_s[8][32][40];        // 20KB, wave-private regions
    __shared__ float X_s[2][4][2][512];     // 32KB [ns][hg][iw][p*64+lane]

    const int n0 = nt * 64;
    const float C = 0.125f * 1.44269504f;   // SCALE * log2(e)

    const __hip_bfloat16* Vb[2] = {
        Vt + (size_t)((bb * 8 + h0)     * 64) * 1024,
        Vt + (size_t)((bb * 8 + h0 + 1) * 64) * 1024 };

    auto stage = [&](int bufn, int mt) {
        #pragma unroll
        for (int i = 0; i < 4; ++i) {
            const int u    = (w * 4 + i) * 64 + lane;   // 16B unit, 0..2047
            const int h    = u >> 8;                    // 256 units per head
            const int mr   = (u >> 3) & 31;             // row within tile
            const int slot = (u & 7) ^ (mr & 7);        // swizzled 16B slot
            const __hip_bfloat16* g =
                K + ((size_t)((bb * 8 + h) * 1024) + mt + mr) * 64 + slot * 8;
            __builtin_amdgcn_global_load_lds(
                (const __attribute__((address_space(1))) unsigned int*)g,
                (__attribute__((address_space(3))) unsigned int*)&K_s[bufn][u * 8],
                16, 0, 0);
        }
    };

    // Q fragments (B operand): qf[ns][hh][kc]
    short8 qf[2][2][2];
    #pragma unroll
    for (int ns = 0; ns < 2; ++ns)
        #pragma unroll
        for (int hh = 0; hh < 2; ++hh)
            #pragma unroll
            for (int kc = 0; kc < 2; ++kc)
                qf[ns][hh][kc] = *reinterpret_cast<const short8*>(
                    Q + ((size_t)((bb * 8 + h0 + hh) * 1024) + n0 + ns * 32 + iw * 16 + l15) * 64
                      + kc * 32 + lg * 8);

    float4v oacc[2][2][4] = {};       // [ns][hh][dd]

    stage(0, 0);
    __syncthreads();                  // drain prologue staging

    for (int it = 0; it < 32; ++it) {
        const int m0  = it << 5;
        const int buf = it & 1;
        // ---- V frags: issue early (global, consumed at PV) ----
        short8 vf[2][4];              // [hh][dd]
        #pragma unroll
        for (int hh = 0; hh < 2; ++hh)
            #pragma unroll
            for (int dd = 0; dd < 4; ++dd)
                vf[hh][dd] = *reinterpret_cast<const short8*>(
                    Vb[hh] + (size_t)(dd * 16 + l15) * 1024 + m0 + lg * 8);
        // ---- K frags from staged LDS (swizzled slots) ----
        short8 kf[2][2][2];           // [hh][j][kc]
        const short* ks = K_s[buf];
        #pragma unroll
        for (int hh = 0; hh < 2; ++hh)
            #pragma unroll
            for (int j = 0; j < 2; ++j) {
                const int mr = j * 16 + l15;
                #pragma unroll
                for (int kc = 0; kc < 2; ++kc)
                    kf[hh][j][kc] = *reinterpret_cast<const short8*>(
                        ks + (h0 + hh) * 2048 + mr * 64
                           + (((kc * 4 + lg) ^ (mr & 7)) * 8));
            }

        #pragma unroll
        for (int ns = 0; ns < 2; ++ns) {
            // ---- S^T = K Q^T, exp in-register ----
            float4v sacc[2][2] = {};  // [hh][j]
            #pragma unroll
            for (int hh = 0; hh < 2; ++hh)
                #pragma unroll
                for (int j = 0; j < 2; ++j)
                    #pragma unroll
                    for (int kc = 0; kc < 2; ++kc)
                        sacc[hh][j] = MFMA16(kf[hh][j][kc], qf[ns][hh][kc], sacc[hh][j]);
            float e[2][8];
            float ps[8] = {0.f, 0.f, 0.f, 0.f, 0.f, 0.f, 0.f, 0.f};
            #pragma unroll
            for (int hh = 0; hh < 2; ++hh)
                #pragma unroll
                for (int j = 0; j < 2; ++j)
                    #pragma unroll
                    for (int r = 0; r < 4; ++r) {
                        float ev = exp2f(sacc[hh][j][r] * C);
                        e[hh][j * 4 + r] = ev;
                        ps[j * 4 + r] += ev;
                    }
            // ---- exchange head-partial sums (scalar, conflict-free) ----
            #pragma unroll
            for (int p = 0; p < 8; ++p)
                X_s[ns][hg][iw][p * 64 + lane] = ps[p];
            __syncthreads();
            if (ns == 0)   // stage next iter's K; drains at end-of-iter barrier
                stage(buf ^ 1, (it < 31) ? m0 + 32 : 0);
            float inv[8];
            #pragma unroll
            for (int p = 0; p < 8; ++p) {
                float tot = ps[p];
                #pragma unroll
                for (int g = 1; g < 4; ++g)
                    tot += X_s[ns][(hg + g) & 3][iw][p * 64 + lane];
                inv[p] = __builtin_amdgcn_rcpf(tot);
            }
            // ---- P = e * inv -> wave-private P_s (b64 packed) ----
            #pragma unroll
            for (int hh = 0; hh < 2; ++hh)
                #pragma unroll
                for (int j = 0; j < 2; ++j) {
                    short4v pk;
                    #pragma unroll
                    for (int r = 0; r < 4; ++r)
                        pk[r] = f2bf(e[hh][j * 4 + r] * inv[j * 4 + r]);
                    *reinterpret_cast<short4v*>(
                        &P_s[h0 + hh][iw * 16 + l15][j * 16 + lg * 4]) = pk;
                }
            // ---- O += P V (P_s wave-private: in-wave LDS ordering suffices) ----
            #pragma unroll
            for (int hh = 0; hh < 2; ++hh) {
                short8 pf = *reinterpret_cast<const short8*>(
                    &P_s[h0 + hh][iw * 16 + l15][lg * 8]);
                #pragma unroll
                for (int dd = 0; dd < 4; ++dd)
                    oacc[ns][hh][dd] = MFMA16(pf, vf[hh][dd], oacc[ns][hh][dd]);
            }
        }
        __syncthreads();              // fences X slots + drains staging DMA
    }

    // ---- epilogue: O[b][n][h*64+d] f32 ----
    #pragma unroll
    for (int ns = 0; ns < 2; ++ns)
        #pragma unroll
        for (int hh = 0; hh < 2; ++hh)
            #pragma unroll
            for (int dd = 0; dd < 4; ++dd)
                #pragma unroll
                for (int r = 0; r < 4; ++r) {
                    const int n = n0 + ns * 32 + iw * 16 + lg * 4 + r;
                    const int d = dd * 16 + l15;
                    O[((size_t)(bb * 1024) + n) * 512 + (h0 + hh) * 64 + d] =
                        oacc[ns][hh][dd][r];
                }
}

extern "C" void kernel_launch(void* const* d_in, const int* in_sizes, int n_in,
                              void* d_out, int out_size, void* d_ws, size_t ws_size,
                              hipStream_t stream) {
    const float* nv = (const float*)d_in[0];
    const float* rv = (const float*)d_in[1];
    const float* Wn = (const float*)d_in[2];
    const float* bn = (const float*)d_in[3];
    const float* Wr = (const float*)d_in[4];
    const float* br = (const float*)d_in[5];
    float* out = (float*)d_out;

    __hip_bfloat16* w = (__hip_bfloat16*)d_ws;
    const size_t E = 8ull * 8 * 1024 * 64;    // 4M elems
    __hip_bfloat16* Qn  = w;
    __hip_bfloat16* Kn  = w + E;
    __hip_bfloat16* Qr  = w + 2 * E;
    __hip_bfloat16* Kr  = w + 3 * E;
    __hip_bfloat16* Vtn = w + 4 * E;
    __hip_bfloat16* Vtr = w + 5 * E;
    __hip_bfloat16* Wtn = w + 6 * E;
    __hip_bfloat16* Wtr = w + 6 * E + 512 * 1024;

    prep_kernel<<<dim3(32, 8, 9), 256, 0, stream>>>(nv, rv, Wn, Wr,
                                                    Vtn, Vtr, Wtn, Wtr);
    proj_kernel<<<dim3(64, 4, 2), 256, 0, stream>>>(nv, rv, Wtn, Wtr, bn, br,
                                                    Qn, Kn, Qr, Kr);
    attn_kernel<<<dim3(16, 16), 512, 0, stream>>>(Qn, Kn, Qr, Kr, Vtn, Vtr, out);
}